// Round 3
// baseline (838.517 us; speedup 1.0000x reference)
//
#include <hip/hip_runtime.h>

typedef short bf16x8 __attribute__((ext_vector_type(8)));
typedef float f32x4 __attribute__((ext_vector_type(4)));

#define MAX_C 400000

// Module-static device scratch (BSS; no dependence on ws_size).
__device__ unsigned short g_W1t[384 * 128];               // W1^T bf16 [n=128][k=384]
__device__ unsigned short g_W2t[128 * 128];               // W2^T bf16 [n=128][k=128]
__device__ unsigned short g_cell[(size_t)MAX_C * 128];    // cell_attr bf16 [C][128]

__device__ __forceinline__ unsigned short f2bf(float f) {
    union { unsigned int i; float f; } v; v.f = f;
    unsigned int r = (v.i + 0x7FFFu + ((v.i >> 16) & 1u)) >> 16;
    return (unsigned short)r;
}

// -------- Phase 1: cell_attr[c] = sum_{j<3} node_attr[cells_node[3c+j]] ------
// cells_index is repeat(arange(C),3): cell c owns slots 3c..3c+2 -> no atomics.
__global__ __launch_bounds__(256) void cell_sum_kernel(
        const float* __restrict__ node_attr,
        const int* __restrict__ cells_node, int C)
{
    int t = threadIdx.x;
    int cell = blockIdx.x * 16 + (t >> 4);   // 16 cells/block, 16 lanes/cell
    int sub = t & 15;                        // 8 floats per lane
    if (cell >= C || cell >= MAX_C) return;
    float acc[8] = {0.f,0.f,0.f,0.f,0.f,0.f,0.f,0.f};
    #pragma unroll
    for (int j = 0; j < 3; ++j) {
        int idx = cells_node[cell * 3 + j];
        const float* p = node_attr + (long)idx * 128 + sub * 8;
        float4 v0 = *(const float4*)(p);
        float4 v1 = *(const float4*)(p + 4);
        acc[0] += v0.x; acc[1] += v0.y; acc[2] += v0.z; acc[3] += v0.w;
        acc[4] += v1.x; acc[5] += v1.y; acc[6] += v1.z; acc[7] += v1.w;
    }
    unsigned short o[8];
    #pragma unroll
    for (int q = 0; q < 8; ++q) o[q] = f2bf(acc[q]);
    *(uint4*)(g_cell + (long)cell * 128 + sub * 8) = *(const uint4*)o;
}

// -------- Weight prep: W1 f32 [384][128] -> bf16 W1t [128][384]; W2 same ----
__global__ __launch_bounds__(256) void wprep_kernel(
        const float* __restrict__ W1,
        const float* __restrict__ W2)
{
    int i = blockIdx.x * 256 + threadIdx.x;   // grid covers 49152 + 16384
    if (i < 384 * 128) {
        int n = i / 384, k = i % 384;
        g_W1t[i] = f2bf(W1[k * 128 + n]);
    } else {
        int j = i - 384 * 128;
        int n = j / 128, k = j % 128;
        g_W2t[j] = f2bf(W2[k * 128 + n]);
    }
}

// -------- Phase 2: gathered 2-layer MLP over edges (MFMA, bf16 internal) ----
// Block = 128 edges x 128 out. 4 waves, wave w owns rows 32w..32w+31 (2x8
// tiles of 16x16x32). A-chunks [128][32] staged in LDS (pad->40 bf16),
// weights pre-transposed bf16 so B-frags are contiguous ds_read_b128.
// h goes through LDS (Hs [128][136]) to convert C-layout -> A-layout.
__global__ __launch_bounds__(256) void edge_mlp_kernel(
        const float* __restrict__ edge_attr,
        const float* __restrict__ b1,
        const float* __restrict__ b2,
        const int* __restrict__ senders,
        const int* __restrict__ receivers,
        float* __restrict__ out, int E)
{
    __shared__ __align__(16) unsigned char smem[1024 + 10240 + 34816];
    int* sIdx = (int*)smem;                                        // [128]
    int* rIdx = (int*)(smem + 512);                                // [128]
    unsigned short* Wts = (unsigned short*)(smem + 1024);          // [128][40]
    unsigned short* As  = (unsigned short*)(smem + 1024 + 10240);  // [128][40] aliases Hs
    unsigned short* Hs  = (unsigned short*)(smem + 1024 + 10240);  // [128][136]

    int t = threadIdx.x;
    int e0 = blockIdx.x * 128;

    if (t < 128) sIdx[t] = senders[min(e0 + t, E - 1)];
    else         rIdx[t - 128] = receivers[min(e0 + t - 128, E - 1)];
    __syncthreads();

    int wv = t >> 6, l = t & 63;
    int lrow = l & 15, quad = l >> 4;

    f32x4 acc[2][8];
    #pragma unroll
    for (int m = 0; m < 2; ++m)
        #pragma unroll
        for (int n = 0; n < 8; ++n) acc[m][n] = (f32x4)(0.f);

    // ---- layer 1: K = 384 in 12 chunks of 32 ----
    for (int kc = 0; kc < 12; ++kc) {
        int kin = (kc & 3) * 32;
        #pragma unroll
        for (int i = 0; i < 2; ++i) {
            int tau = t + i * 256;
            int row = tau >> 2;         // 0..127
            int koff = (tau & 3) * 8;   // 0,8,16,24
            uint4 v;
            if (kc < 4) {
                v = *(const uint4*)(g_cell + (long)sIdx[row] * 128 + kin + koff);
            } else if (kc < 8) {
                if (sIdx[row] == rIdx[row]) v = make_uint4(0u, 0u, 0u, 0u);
                else v = *(const uint4*)(g_cell + (long)rIdx[row] * 128 + kin + koff);
            } else {
                int e = min(e0 + row, E - 1);
                const float* p = edge_attr + (long)e * 128 + kin + koff;
                float4 f0 = *(const float4*)(p);
                float4 f1 = *(const float4*)(p + 4);
                unsigned short tmp[8];
                tmp[0] = f2bf(f0.x); tmp[1] = f2bf(f0.y);
                tmp[2] = f2bf(f0.z); tmp[3] = f2bf(f0.w);
                tmp[4] = f2bf(f1.x); tmp[5] = f2bf(f1.y);
                tmp[6] = f2bf(f1.z); tmp[7] = f2bf(f1.w);
                v = *(const uint4*)tmp;
            }
            *(uint4*)(As + row * 40 + koff) = v;
            uint4 w = *(const uint4*)(g_W1t + (long)row * 384 + kc * 32 + koff);
            *(uint4*)(Wts + row * 40 + koff) = w;
        }
        __syncthreads();
        bf16x8 a0 = *(const bf16x8*)(As + (wv * 32 + lrow) * 40 + quad * 8);
        bf16x8 a1 = *(const bf16x8*)(As + (wv * 32 + 16 + lrow) * 40 + quad * 8);
        #pragma unroll
        for (int nt = 0; nt < 8; ++nt) {
            bf16x8 b = *(const bf16x8*)(Wts + (nt * 16 + lrow) * 40 + quad * 8);
            acc[0][nt] = __builtin_amdgcn_mfma_f32_16x16x32_bf16(a0, b, acc[0][nt], 0, 0, 0);
            acc[1][nt] = __builtin_amdgcn_mfma_f32_16x16x32_bf16(a1, b, acc[1][nt], 0, 0, 0);
        }
        __syncthreads();
    }

    // ---- epilogue 1: bias + relu -> Hs (bf16, C-layout -> row-major) ----
    #pragma unroll
    for (int m = 0; m < 2; ++m) {
        int rbase = wv * 32 + m * 16 + quad * 4;
        #pragma unroll
        for (int nt = 0; nt < 8; ++nt) {
            int n = nt * 16 + lrow;
            float bias = b1[n];
            #pragma unroll
            for (int r = 0; r < 4; ++r) {
                float v = acc[m][nt][r] + bias;
                v = v > 0.f ? v : 0.f;
                Hs[(rbase + r) * 136 + n] = f2bf(v);
            }
        }
    }
    __syncthreads();

    // ---- layer 2: K = 128 in 4 chunks of 32 ----
    f32x4 acc2[2][8];
    #pragma unroll
    for (int m = 0; m < 2; ++m)
        #pragma unroll
        for (int n = 0; n < 8; ++n) acc2[m][n] = (f32x4)(0.f);

    for (int kc = 0; kc < 4; ++kc) {
        #pragma unroll
        for (int i = 0; i < 2; ++i) {
            int tau = t + i * 256;
            int row = tau >> 2;
            int koff = (tau & 3) * 8;
            uint4 w = *(const uint4*)(g_W2t + (long)row * 128 + kc * 32 + koff);
            *(uint4*)(Wts + row * 40 + koff) = w;
        }
        __syncthreads();
        bf16x8 a0 = *(const bf16x8*)(Hs + (wv * 32 + lrow) * 136 + kc * 32 + quad * 8);
        bf16x8 a1 = *(const bf16x8*)(Hs + (wv * 32 + 16 + lrow) * 136 + kc * 32 + quad * 8);
        #pragma unroll
        for (int nt = 0; nt < 8; ++nt) {
            bf16x8 b = *(const bf16x8*)(Wts + (nt * 16 + lrow) * 40 + quad * 8);
            acc2[0][nt] = __builtin_amdgcn_mfma_f32_16x16x32_bf16(a0, b, acc2[0][nt], 0, 0, 0);
            acc2[1][nt] = __builtin_amdgcn_mfma_f32_16x16x32_bf16(a1, b, acc2[1][nt], 0, 0, 0);
        }
        __syncthreads();
    }

    // ---- epilogue 2: bias -> out (f32) ----
    #pragma unroll
    for (int m = 0; m < 2; ++m) {
        int rbase = wv * 32 + m * 16 + quad * 4;
        #pragma unroll
        for (int nt = 0; nt < 8; ++nt) {
            int n = nt * 16 + lrow;
            float bias = b2[n];
            #pragma unroll
            for (int r = 0; r < 4; ++r) {
                int e = e0 + rbase + r;
                if (e < E) out[(long)e * 128 + n] = acc2[m][nt][r] + bias;
            }
        }
    }
}

extern "C" void kernel_launch(void* const* d_in, const int* in_sizes, int n_in,
                              void* d_out, int out_size, void* d_ws, size_t ws_size,
                              hipStream_t stream)
{
    const float* node_attr = (const float*)d_in[0];
    const float* edge_attr = (const float*)d_in[1];
    const float* W1 = (const float*)d_in[2];
    const float* b1 = (const float*)d_in[3];
    const float* W2 = (const float*)d_in[4];
    const float* b2 = (const float*)d_in[5];
    const int* cells_node  = (const int*)d_in[6];
    const int* edge_index  = (const int*)d_in[8];
    float* out = (float*)d_out;

    int E = in_sizes[1] / 128;
    int C = in_sizes[6] / 3;

    const int* senders = edge_index;
    const int* receivers = edge_index + E;

    hipLaunchKernelGGL(cell_sum_kernel, dim3((C + 15) / 16), dim3(256), 0, stream,
                       node_attr, cells_node, C);
    hipLaunchKernelGGL(wprep_kernel, dim3((384 * 128 + 128 * 128) / 256), dim3(256), 0, stream,
                       W1, W2);
    hipLaunchKernelGGL(edge_mlp_kernel, dim3((E + 127) / 128), dim3(256), 0, stream,
                       edge_attr, b1, b2, senders, receivers, out, E);
}